// Round 6
// baseline (2996.249 us; speedup 1.0000x reference)
//
#include <hip/hip_runtime.h>
#include <math.h>

#define NB 4096
#define ND 256
#define NH 64
#define NK 32
#define NC 10
#define TAU 0.3f

// Chunked workspace layout (floats); nbc (chunk batch) and kspl (pred split-K)
// chosen at launch from ws_size (ws_size is call-invariant -> same work/call):
//  misc : 16384          A_rm[256*32] | Sg[32*32] | ca[32] | d_[256]
//  V    : nbc*2048       [nbc][32][64] rank-32 bottleneck
//  h    : nbc*16384      [nbc][256][64] node states (in place across rounds)
//  part : nbc*kspl*128   [kspl][nbc][128] pred split-K partials
//  u    : nbc*128        relu hidden
// tiers: nbc=4096:338MB 2048:185MB 1024:109MB 512:71MB 256:53MB min:21MB

// ---------------------------------------------------------------------------
// k_prep: one block, 4KB LDS. Thread t owns softmax row t (in VGPRs).
// d_[t] = sum_p (A@S)[t,p]*A[t,p]. ca[t<32] = colsum(A) re-read from global
// A_rm (block-visible after __syncthreads).
// ---------------------------------------------------------------------------
__global__ __launch_bounds__(256) void k_prep(const float* __restrict__ A_raw,
                                              const float* __restrict__ priority,
                                              const float* __restrict__ edge_logits,
                                              float* __restrict__ A_rm,
                                              float* __restrict__ Sg,
                                              float* __restrict__ ca,
                                              float* __restrict__ d_) {
  __shared__ float Ss[NK][NK];
  int t = threadIdx.x;
  float a[NK];
  {
    float mx = -1e30f;
    #pragma unroll
    for (int q = 0; q < NK; ++q) { a[q] = A_raw[t * NK + q]; mx = fmaxf(mx, a[q]); }
    float s = 0.f;
    #pragma unroll
    for (int q = 0; q < NK; ++q) { a[q] = expf(a[q] - mx); s += a[q]; }
    float inv = 1.f / s;
    #pragma unroll
    for (int q = 0; q < NK; ++q) {
      a[q] *= inv;
      A_rm[t * NK + q] = a[q];
    }
  }
  for (int s = t; s < NK * NK; s += 256) {
    int p = s >> 5, q = s & 31;
    float dir = 1.f / (1.f + expf(-(priority[q] - priority[p]) / TAU));
    float edge = (edge_logits[s] > 0.f) ? 1.f : 0.f;
    float sv = (p == q) ? 0.f : edge * dir;
    Ss[p][q] = sv;
    Sg[s] = sv;
  }
  __syncthreads();
  {
    float dd = 0.f;
    #pragma unroll
    for (int p = 0; p < NK; ++p) {
      float m = 0.f;
      #pragma unroll
      for (int q = 0; q < NK; ++q) m = fmaf(a[q], Ss[q][p], m);
      dd = fmaf(m, a[p], dd);
    }
    d_[t] = dd;
  }
  if (t < NK) {
    float s = 0.f;
    for (int jj = 0; jj < ND; ++jj) s += A_rm[jj * NK + t];
    ca[t] = s;
  }
}

// ---------------------------------------------------------------------------
// k_r1: per chunk-batch (1 wave): V[b] = S^T ( (A^T h[b]) @ aw + ca (x) ab ).
// Thread tile 4p x 8u; T,U relayed through 17.4KB LDS.
// ---------------------------------------------------------------------------
template <bool FROMX>
__global__ __launch_bounds__(64) void k_r1(const float* __restrict__ hbuf,
                                           const float* __restrict__ x,
                                           const float* __restrict__ wn,
                                           const float* __restrict__ bn,
                                           const float* __restrict__ A_rm,
                                           const float* __restrict__ Sg,
                                           const float* __restrict__ ca,
                                           const float* __restrict__ aw,
                                           const float* __restrict__ ab,
                                           float* __restrict__ Vg) {
  __shared__ float Tl[NK][68];
  __shared__ float Ul[NK][68];
  int b = blockIdx.x;
  int t = threadIdx.x;
  int ug = t & 7, pg = t >> 3;
  int p0 = pg * 4, u0 = ug * 8;

  float acc[4][8];
  #pragma unroll
  for (int k = 0; k < 4; ++k)
    #pragma unroll
    for (int m = 0; m < 8; ++m) acc[k][m] = 0.f;

  const float* hb = hbuf + (size_t)b * ND * NH;
  for (int i = 0; i < ND; ++i) {
    float hv[8];
    if (FROMX) {
      float xv = x[b * ND + i];
      float4 w0 = *(const float4*)(wn + i * NH + u0);
      float4 w1 = *(const float4*)(wn + i * NH + u0 + 4);
      float4 c0 = *(const float4*)(bn + i * NH + u0);
      float4 c1 = *(const float4*)(bn + i * NH + u0 + 4);
      hv[0] = fmaf(xv, w0.x, c0.x); hv[1] = fmaf(xv, w0.y, c0.y);
      hv[2] = fmaf(xv, w0.z, c0.z); hv[3] = fmaf(xv, w0.w, c0.w);
      hv[4] = fmaf(xv, w1.x, c1.x); hv[5] = fmaf(xv, w1.y, c1.y);
      hv[6] = fmaf(xv, w1.z, c1.z); hv[7] = fmaf(xv, w1.w, c1.w);
    } else {
      float4 h0 = *(const float4*)(hb + (size_t)i * NH + u0);
      float4 h1 = *(const float4*)(hb + (size_t)i * NH + u0 + 4);
      hv[0] = h0.x; hv[1] = h0.y; hv[2] = h0.z; hv[3] = h0.w;
      hv[4] = h1.x; hv[5] = h1.y; hv[6] = h1.z; hv[7] = h1.w;
    }
    float4 a4 = *(const float4*)(A_rm + i * NK + p0);
    float ap[4] = {a4.x, a4.y, a4.z, a4.w};
    #pragma unroll
    for (int k = 0; k < 4; ++k)
      #pragma unroll
      for (int m = 0; m < 8; ++m) acc[k][m] = fmaf(ap[k], hv[m], acc[k][m]);
  }
  #pragma unroll
  for (int k = 0; k < 4; ++k) {
    *(float4*)&Tl[p0 + k][u0]     = make_float4(acc[k][0], acc[k][1], acc[k][2], acc[k][3]);
    *(float4*)&Tl[p0 + k][u0 + 4] = make_float4(acc[k][4], acc[k][5], acc[k][6], acc[k][7]);
  }
  __syncthreads();
  float ua[4][8];
  {
    float4 b0 = *(const float4*)(ab + u0);
    float4 b1 = *(const float4*)(ab + u0 + 4);
    float abv[8] = {b0.x, b0.y, b0.z, b0.w, b1.x, b1.y, b1.z, b1.w};
    float4 c4 = *(const float4*)(ca + p0);
    float cav[4] = {c4.x, c4.y, c4.z, c4.w};
    #pragma unroll
    for (int k = 0; k < 4; ++k)
      #pragma unroll
      for (int m = 0; m < 8; ++m) ua[k][m] = cav[k] * abv[m];
  }
  for (int v = 0; v < NH; ++v) {
    float4 w0 = *(const float4*)(aw + v * NH + u0);
    float4 w1 = *(const float4*)(aw + v * NH + u0 + 4);
    float wv[8] = {w0.x, w0.y, w0.z, w0.w, w1.x, w1.y, w1.z, w1.w};
    float tv[4];
    #pragma unroll
    for (int k = 0; k < 4; ++k) tv[k] = Tl[p0 + k][v];
    #pragma unroll
    for (int k = 0; k < 4; ++k)
      #pragma unroll
      for (int m = 0; m < 8; ++m) ua[k][m] = fmaf(tv[k], wv[m], ua[k][m]);
  }
  #pragma unroll
  for (int k = 0; k < 4; ++k) {
    *(float4*)&Ul[p0 + k][u0]     = make_float4(ua[k][0], ua[k][1], ua[k][2], ua[k][3]);
    *(float4*)&Ul[p0 + k][u0 + 4] = make_float4(ua[k][4], ua[k][5], ua[k][6], ua[k][7]);
  }
  __syncthreads();
  float va[4][8];
  #pragma unroll
  for (int k = 0; k < 4; ++k)
    #pragma unroll
    for (int m = 0; m < 8; ++m) va[k][m] = 0.f;
  for (int p = 0; p < NK; ++p) {
    float4 u0v = *(const float4*)&Ul[p][u0];
    float4 u1v = *(const float4*)&Ul[p][u0 + 4];
    float uv[8] = {u0v.x, u0v.y, u0v.z, u0v.w, u1v.x, u1v.y, u1v.z, u1v.w};
    float4 s4 = *(const float4*)(Sg + p * NK + p0);
    float sv[4] = {s4.x, s4.y, s4.z, s4.w};
    #pragma unroll
    for (int k = 0; k < 4; ++k)
      #pragma unroll
      for (int m = 0; m < 8; ++m) va[k][m] = fmaf(sv[k], uv[m], va[k][m]);
  }
  #pragma unroll
  for (int k = 0; k < 4; ++k) {
    float* vp = Vg + ((size_t)b * NK + p0 + k) * NH + u0;
    *(float4*)vp       = make_float4(va[k][0], va[k][1], va[k][2], va[k][3]);
    *(float4*)(vp + 4) = make_float4(va[k][4], va[k][5], va[k][6], va[k][7]);
  }
}

// ---------------------------------------------------------------------------
// k_upd: thread = one row j of chunk-batch b; row-local given V[b]; weights
// wave-uniform (s_load path); no LDS, no barriers.
// ---------------------------------------------------------------------------
template <bool FROMX>
__global__ __launch_bounds__(256, 2) void k_upd(float* __restrict__ hbuf,
                                                const float* __restrict__ x,
                                                const float* __restrict__ wn,
                                                const float* __restrict__ bn,
                                                const float* __restrict__ A_rm,
                                                const float* __restrict__ d_,
                                                const float* __restrict__ Vg,
                                                const float* __restrict__ aw,
                                                const float* __restrict__ ab,
                                                const float* __restrict__ w1,
                                                const float* __restrict__ b1,
                                                const float* __restrict__ w2,
                                                const float* __restrict__ b2) {
  int b = blockIdx.x, j = threadIdx.x;
  float* hrow = hbuf + ((size_t)b * ND + j) * NH;
  float h[NH], msg[NH], out[NH];
  if (FROMX) {
    float xv = x[b * ND + j];
    #pragma unroll
    for (int q = 0; q < 16; ++q) {
      float4 w = *(const float4*)(wn + j * NH + q * 4);
      float4 c = *(const float4*)(bn + j * NH + q * 4);
      h[q * 4 + 0] = fmaf(xv, w.x, c.x);
      h[q * 4 + 1] = fmaf(xv, w.y, c.y);
      h[q * 4 + 2] = fmaf(xv, w.z, c.z);
      h[q * 4 + 3] = fmaf(xv, w.w, c.w);
    }
  } else {
    #pragma unroll
    for (int q = 0; q < 16; ++q) {
      float4 v = *(const float4*)(hrow + q * 4);
      h[q * 4 + 0] = v.x; h[q * 4 + 1] = v.y; h[q * 4 + 2] = v.z; h[q * 4 + 3] = v.w;
    }
  }
  #pragma unroll
  for (int u = 0; u < NH; ++u) msg[u] = ab[u];
  #pragma unroll
  for (int v = 0; v < NH; ++v) {
    float hv = h[v];
    #pragma unroll
    for (int u = 0; u < NH; ++u) msg[u] = fmaf(hv, aw[v * NH + u], msg[u]);
  }
  float dj = d_[j];
  #pragma unroll
  for (int u = 0; u < NH; ++u) msg[u] *= -dj;
  const float* Vb = Vg + (size_t)b * NK * NH;
  #pragma unroll
  for (int pq = 0; pq < NK / 4; ++pq) {
    float4 a4 = *(const float4*)(A_rm + j * NK + pq * 4);
    float ap[4] = {a4.x, a4.y, a4.z, a4.w};
    #pragma unroll
    for (int k = 0; k < 4; ++k) {
      float av = ap[k];
      #pragma unroll
      for (int u = 0; u < NH; ++u)
        msg[u] = fmaf(av, Vb[(pq * 4 + k) * NH + u], msg[u]);
    }
  }
  #pragma unroll
  for (int u = 0; u < NH; ++u) out[u] = b2[u];
  for (int vg = 0; vg < 8; ++vg) {   // runtime loop: only weight addrs use vg
    float t8[8];
    #pragma unroll
    for (int k = 0; k < 8; ++k) t8[k] = b1[vg * 8 + k];
    #pragma unroll
    for (int u = 0; u < NH; ++u) {
      float zu = h[u];
      #pragma unroll
      for (int k = 0; k < 8; ++k)
        t8[k] = fmaf(zu, w1[u * NH + vg * 8 + k], t8[k]);
    }
    #pragma unroll
    for (int u = 0; u < NH; ++u) {
      float zu = msg[u];
      #pragma unroll
      for (int k = 0; k < 8; ++k)
        t8[k] = fmaf(zu, w1[(NH + u) * NH + vg * 8 + k], t8[k]);
    }
    #pragma unroll
    for (int k = 0; k < 8; ++k) {
      float tv = fmaxf(t8[k], 0.f);
      #pragma unroll
      for (int u = 0; u < NH; ++u)
        out[u] = fmaf(tv, w2[(vg * 8 + k) * NH + u], out[u]);
    }
  }
  #pragma unroll
  for (int q = 0; q < 16; ++q)
    *(float4*)(hrow + q * 4) =
        make_float4(out[q * 4], out[q * 4 + 1], out[q * 4 + 2], out[q * 4 + 3]);
}

// ---------------------------------------------------------------------------
// k_pred1: thread = (chunk-batch, K-split). out[128] in VGPRs.
// ks from blockIdx>>lbps (uniform -> s_load weights), b from tid (per-lane).
// grid = kspl * (nbc/256) blocks.
// ---------------------------------------------------------------------------
__global__ __launch_bounds__(256) void k_pred1(const float* __restrict__ h,
                                               const float* __restrict__ p1w,
                                               float* __restrict__ part,
                                               int lbps, int kch, int nbc) {
  int ks = blockIdx.x >> lbps;                 // uniform
  int bi = blockIdx.x & ((1 << lbps) - 1);
  int b  = (bi << 8) | threadIdx.x;            // per-lane, < nbc
  const float* hrow  = h + (size_t)b * (ND * NH) + (size_t)ks * kch;
  const float* wbase = p1w + (size_t)ks * kch * 128;
  float out[128];
  #pragma unroll
  for (int c = 0; c < 128; ++c) out[c] = 0.f;
  int kch8 = kch >> 3;
  for (int k8 = 0; k8 < kch8; ++k8) {
    float4 h0 = *(const float4*)(hrow + k8 * 8);
    float4 h1 = *(const float4*)(hrow + k8 * 8 + 4);
    float hv[8] = {h0.x, h0.y, h0.z, h0.w, h1.x, h1.y, h1.z, h1.w};
    #pragma unroll
    for (int kk = 0; kk < 8; ++kk) {
      const float* wrow = wbase + ((size_t)k8 * 8 + kk) * 128;
      float hvv = hv[kk];
      #pragma unroll
      for (int c = 0; c < 128; ++c) out[c] = fmaf(hvv, wrow[c], out[c]);
    }
  }
  float* pp = part + ((size_t)ks * nbc + b) * 128;
  #pragma unroll
  for (int c = 0; c < 32; ++c)
    *(float4*)(pp + c * 4) =
        make_float4(out[c * 4], out[c * 4 + 1], out[c * 4 + 2], out[c * 4 + 3]);
}

// ---------------------------------------------------------------------------
__global__ __launch_bounds__(256) void k_reduce(const float* __restrict__ part,
                                                const float* __restrict__ p1b,
                                                float* __restrict__ u,
                                                int kspl, int stride) {
  int idx = blockIdx.x * 256 + threadIdx.x;    // < nbc*128
  float acc = p1b[idx & 127];
  for (int ks = 0; ks < kspl; ++ks) acc += part[(size_t)ks * stride + idx];
  u[idx] = fmaxf(acc, 0.f);
}

// ---------------------------------------------------------------------------
// k_pred2: thread = one batch row; all p2w/p2b loads wave-uniform.
// ---------------------------------------------------------------------------
__global__ __launch_bounds__(256) void k_pred2(const float* __restrict__ u,
                                               const float* __restrict__ p2w,
                                               const float* __restrict__ p2b,
                                               float* __restrict__ out) {
  int b = blockIdx.x * 256 + threadIdx.x;
  const float* ub = u + (size_t)b * 128;
  float acc[NC];
  #pragma unroll
  for (int c = 0; c < NC; ++c) acc[c] = p2b[c];
  #pragma unroll
  for (int q = 0; q < 32; ++q) {
    float4 uv = *(const float4*)(ub + q * 4);
    float us[4] = {uv.x, uv.y, uv.z, uv.w};
    #pragma unroll
    for (int k = 0; k < 4; ++k) {
      const float* wr = p2w + (q * 4 + k) * NC;
      #pragma unroll
      for (int c = 0; c < NC; ++c) acc[c] = fmaf(us[k], wr[c], acc[c]);
    }
  }
  float* op = out + (size_t)b * NC;
  #pragma unroll
  for (int c = 0; c < NC; ++c) op[c] = acc[c];
}

// ---------------------------------------------------------------------------
extern "C" void kernel_launch(void* const* d_in, const int* in_sizes, int n_in,
                              void* d_out, int out_size, void* d_ws, size_t ws_size,
                              hipStream_t stream) {
  const float* x           = (const float*)d_in[0];
  const float* wn          = (const float*)d_in[1];
  const float* bn          = (const float*)d_in[2];
  const float* A_raw       = (const float*)d_in[3];
  const float* priority    = (const float*)d_in[4];
  const float* edge_logits = (const float*)d_in[5];
  const float* agg_w       = (const float*)d_in[6];
  const float* agg_b       = (const float*)d_in[7];
  const float* upd_w1      = (const float*)d_in[8];
  const float* upd_b1      = (const float*)d_in[9];
  const float* upd_w2      = (const float*)d_in[10];
  const float* upd_b2      = (const float*)d_in[11];
  const float* p1w         = (const float*)d_in[12];
  const float* p1b         = (const float*)d_in[13];
  const float* p2w         = (const float*)d_in[14];
  const float* p2b         = (const float*)d_in[15];
  float* out               = (float*)d_out;

  // pick the largest (nbc, kspl) tier whose workspace fits ws_size
  int nbc = 0, kspl = 0;
  for (int cand = NB; cand >= 256 && !nbc; cand >>= 1) {
    size_t fl = 16384ull + (size_t)cand * 2048 + (size_t)cand * 16384 +
                (size_t)cand * (65536 / cand) * 128 + (size_t)cand * 128;
    if (fl * 4 <= ws_size) { nbc = cand; kspl = 65536 / cand; }
  }
  if (!nbc) { nbc = 256; kspl = 16; }    // minimal tier (~21MB)
  int nch  = NB / nbc;
  int kch  = 16384 / kspl;               // K elements per split
  int lbps = 0;                          // log2(blocks per split)
  for (int v = nbc >> 8; v > 1; v >>= 1) ++lbps;

  float* ws   = (float*)d_ws;
  float* A_rm = ws;                                  // 8192
  float* Sg   = ws + 8192;                           // 1024
  float* ca   = ws + 9216;                           // 64
  float* d_   = ws + 9280;                           // 256
  float* V    = ws + 16384;                          // nbc*2048
  float* h    = V + (size_t)nbc * 2048;              // nbc*16384
  float* part = h + (size_t)nbc * 16384;             // nbc*kspl*128
  float* u    = part + (size_t)nbc * kspl * 128;     // nbc*128

  hipLaunchKernelGGL(k_prep, dim3(1), dim3(256), 0, stream,
                     A_raw, priority, edge_logits, A_rm, Sg, ca, d_);

  for (int c = 0; c < nch; ++c) {
    const float* xc = x + (size_t)c * nbc * ND;
    float* outc = out + (size_t)c * nbc * NC;
    // round 0 (h built from x on the fly)
    hipLaunchKernelGGL((k_r1<true>), dim3(nbc), dim3(64), 0, stream,
                       h, xc, wn, bn, A_rm, Sg, ca, agg_w, agg_b, V);
    hipLaunchKernelGGL((k_upd<true>), dim3(nbc), dim3(256), 0, stream,
                       h, xc, wn, bn, A_rm, d_, V, agg_w, agg_b,
                       upd_w1, upd_b1, upd_w2, upd_b2);
    // round 1
    hipLaunchKernelGGL((k_r1<false>), dim3(nbc), dim3(64), 0, stream,
                       h, xc, wn, bn, A_rm, Sg, ca,
                       agg_w + NH * NH, agg_b + NH, V);
    hipLaunchKernelGGL((k_upd<false>), dim3(nbc), dim3(256), 0, stream,
                       h, xc, wn, bn, A_rm, d_, V,
                       agg_w + NH * NH, agg_b + NH,
                       upd_w1 + 2 * NH * NH, upd_b1 + NH,
                       upd_w2 + NH * NH, upd_b2 + NH);
    // predictor
    hipLaunchKernelGGL(k_pred1, dim3(kspl * (nbc >> 8)), dim3(256), 0, stream,
                       h, p1w, part, lbps, kch, nbc);
    hipLaunchKernelGGL(k_reduce, dim3(nbc * 128 / 256), dim3(256), 0, stream,
                       part, p1b, u, kspl, nbc * 128);
    hipLaunchKernelGGL(k_pred2, dim3(nbc / 256), dim3(256), 0, stream,
                       u, p2w, p2b, outc);
  }
}

// Round 10
// 1740.048 us; speedup vs baseline: 1.7219x; 1.7219x over previous
//
#include <hip/hip_runtime.h>
#include <math.h>

#define NB 4096
#define ND 256
#define NH 64
#define NK 32
#define NC 10
#define TAU 0.3f

// Workspace (floats): misc 16384 | V nbc*2048 | h nbc*16384 | part 4194304 | u nbc*128
// tiers: nbc=4096:321MB 2048:169MB 1024:93MB 512:55MB 256:36MB

// ---------------------------------------------------------------------------
// 4x4 micro-tile FMA: acc[i][j] += sum_k a_i[k] * b_k[j]
// ---------------------------------------------------------------------------
__device__ __forceinline__ void mm4(float (&acc)[4][4],
                                    const float4 a0, const float4 a1,
                                    const float4 a2, const float4 a3,
                                    const float4 b0, const float4 b1,
                                    const float4 b2, const float4 b3) {
#define MM4_ROW(ai, I)                                                          \
  acc[I][0] = fmaf(ai.x, b0.x, fmaf(ai.y, b1.x, fmaf(ai.z, b2.x, fmaf(ai.w, b3.x, acc[I][0])))); \
  acc[I][1] = fmaf(ai.x, b0.y, fmaf(ai.y, b1.y, fmaf(ai.z, b2.y, fmaf(ai.w, b3.y, acc[I][1])))); \
  acc[I][2] = fmaf(ai.x, b0.z, fmaf(ai.y, b1.z, fmaf(ai.z, b2.z, fmaf(ai.w, b3.z, acc[I][2])))); \
  acc[I][3] = fmaf(ai.x, b0.w, fmaf(ai.y, b1.w, fmaf(ai.z, b2.w, fmaf(ai.w, b3.w, acc[I][3]))));
  MM4_ROW(a0, 0) MM4_ROW(a1, 1) MM4_ROW(a2, 2) MM4_ROW(a3, 3)
#undef MM4_ROW
}

// ---------------------------------------------------------------------------
// k_prep: one block, 4KB LDS. Thread t owns softmax row t (VGPRs).
// ---------------------------------------------------------------------------
__global__ __launch_bounds__(256) void k_prep(const float* __restrict__ A_raw,
                                              const float* __restrict__ priority,
                                              const float* __restrict__ edge_logits,
                                              float* __restrict__ A_rm,
                                              float* __restrict__ Sg,
                                              float* __restrict__ ca,
                                              float* __restrict__ d_) {
  __shared__ float Ss[NK][NK];
  int t = threadIdx.x;
  float a[NK];
  {
    float mx = -1e30f;
    #pragma unroll
    for (int q = 0; q < NK; ++q) { a[q] = A_raw[t * NK + q]; mx = fmaxf(mx, a[q]); }
    float s = 0.f;
    #pragma unroll
    for (int q = 0; q < NK; ++q) { a[q] = expf(a[q] - mx); s += a[q]; }
    float inv = 1.f / s;
    #pragma unroll
    for (int q = 0; q < NK; ++q) {
      a[q] *= inv;
      A_rm[t * NK + q] = a[q];
    }
  }
  for (int s = t; s < NK * NK; s += 256) {
    int p = s >> 5, q = s & 31;
    float dir = 1.f / (1.f + expf(-(priority[q] - priority[p]) / TAU));
    float edge = (edge_logits[s] > 0.f) ? 1.f : 0.f;
    float sv = (p == q) ? 0.f : edge * dir;
    Ss[p][q] = sv;
    Sg[s] = sv;
  }
  __syncthreads();
  {
    float dd = 0.f;
    #pragma unroll
    for (int p = 0; p < NK; ++p) {
      float m = 0.f;
      #pragma unroll
      for (int q = 0; q < NK; ++q) m = fmaf(a[q], Ss[q][p], m);
      dd = fmaf(m, a[p], dd);
    }
    d_[t] = dd;
  }
  if (t < NK) {
    float s = 0.f;
    for (int jj = 0; jj < ND; ++jj) s += A_rm[jj * NK + t];
    ca[t] = s;
  }
}

// ---------------------------------------------------------------------------
// k_r1: per chunk-batch (1 wave): V[b] = S^T ( (A^T h[b]) @ aw + ca (x) ab ).
// ---------------------------------------------------------------------------
template <bool FROMX>
__global__ __launch_bounds__(64) void k_r1(const float* __restrict__ hbuf,
                                           const float* __restrict__ x,
                                           const float* __restrict__ wn,
                                           const float* __restrict__ bn,
                                           const float* __restrict__ A_rm,
                                           const float* __restrict__ Sg,
                                           const float* __restrict__ ca,
                                           const float* __restrict__ aw,
                                           const float* __restrict__ ab,
                                           float* __restrict__ Vg) {
  __shared__ float Tl[NK][68];
  __shared__ float Ul[NK][68];
  int b = blockIdx.x;
  int t = threadIdx.x;
  int ug = t & 7, pg = t >> 3;
  int p0 = pg * 4, u0 = ug * 8;

  float acc[4][8];
  #pragma unroll
  for (int k = 0; k < 4; ++k)
    #pragma unroll
    for (int m = 0; m < 8; ++m) acc[k][m] = 0.f;

  const float* hb = hbuf + (size_t)b * ND * NH;
  for (int i = 0; i < ND; ++i) {
    float hv[8];
    if (FROMX) {
      float xv = x[b * ND + i];
      float4 w0 = *(const float4*)(wn + i * NH + u0);
      float4 w1 = *(const float4*)(wn + i * NH + u0 + 4);
      float4 c0 = *(const float4*)(bn + i * NH + u0);
      float4 c1 = *(const float4*)(bn + i * NH + u0 + 4);
      hv[0] = fmaf(xv, w0.x, c0.x); hv[1] = fmaf(xv, w0.y, c0.y);
      hv[2] = fmaf(xv, w0.z, c0.z); hv[3] = fmaf(xv, w0.w, c0.w);
      hv[4] = fmaf(xv, w1.x, c1.x); hv[5] = fmaf(xv, w1.y, c1.y);
      hv[6] = fmaf(xv, w1.z, c1.z); hv[7] = fmaf(xv, w1.w, c1.w);
    } else {
      float4 h0 = *(const float4*)(hb + (size_t)i * NH + u0);
      float4 h1 = *(const float4*)(hb + (size_t)i * NH + u0 + 4);
      hv[0] = h0.x; hv[1] = h0.y; hv[2] = h0.z; hv[3] = h0.w;
      hv[4] = h1.x; hv[5] = h1.y; hv[6] = h1.z; hv[7] = h1.w;
    }
    float4 a4 = *(const float4*)(A_rm + i * NK + p0);
    float ap[4] = {a4.x, a4.y, a4.z, a4.w};
    #pragma unroll
    for (int k = 0; k < 4; ++k)
      #pragma unroll
      for (int m = 0; m < 8; ++m) acc[k][m] = fmaf(ap[k], hv[m], acc[k][m]);
  }
  #pragma unroll
  for (int k = 0; k < 4; ++k) {
    *(float4*)&Tl[p0 + k][u0]     = make_float4(acc[k][0], acc[k][1], acc[k][2], acc[k][3]);
    *(float4*)&Tl[p0 + k][u0 + 4] = make_float4(acc[k][4], acc[k][5], acc[k][6], acc[k][7]);
  }
  __syncthreads();
  float ua[4][8];
  {
    float4 b0 = *(const float4*)(ab + u0);
    float4 b1 = *(const float4*)(ab + u0 + 4);
    float abv[8] = {b0.x, b0.y, b0.z, b0.w, b1.x, b1.y, b1.z, b1.w};
    float4 c4 = *(const float4*)(ca + p0);
    float cav[4] = {c4.x, c4.y, c4.z, c4.w};
    #pragma unroll
    for (int k = 0; k < 4; ++k)
      #pragma unroll
      for (int m = 0; m < 8; ++m) ua[k][m] = cav[k] * abv[m];
  }
  for (int v = 0; v < NH; ++v) {
    float4 w0 = *(const float4*)(aw + v * NH + u0);
    float4 w1 = *(const float4*)(aw + v * NH + u0 + 4);
    float wv[8] = {w0.x, w0.y, w0.z, w0.w, w1.x, w1.y, w1.z, w1.w};
    float tv[4];
    #pragma unroll
    for (int k = 0; k < 4; ++k) tv[k] = Tl[p0 + k][v];
    #pragma unroll
    for (int k = 0; k < 4; ++k)
      #pragma unroll
      for (int m = 0; m < 8; ++m) ua[k][m] = fmaf(tv[k], wv[m], ua[k][m]);
  }
  #pragma unroll
  for (int k = 0; k < 4; ++k) {
    *(float4*)&Ul[p0 + k][u0]     = make_float4(ua[k][0], ua[k][1], ua[k][2], ua[k][3]);
    *(float4*)&Ul[p0 + k][u0 + 4] = make_float4(ua[k][4], ua[k][5], ua[k][6], ua[k][7]);
  }
  __syncthreads();
  float va[4][8];
  #pragma unroll
  for (int k = 0; k < 4; ++k)
    #pragma unroll
    for (int m = 0; m < 8; ++m) va[k][m] = 0.f;
  for (int p = 0; p < NK; ++p) {
    float4 u0v = *(const float4*)&Ul[p][u0];
    float4 u1v = *(const float4*)&Ul[p][u0 + 4];
    float uv[8] = {u0v.x, u0v.y, u0v.z, u0v.w, u1v.x, u1v.y, u1v.z, u1v.w};
    float4 s4 = *(const float4*)(Sg + p * NK + p0);
    float sv[4] = {s4.x, s4.y, s4.z, s4.w};
    #pragma unroll
    for (int k = 0; k < 4; ++k)
      #pragma unroll
      for (int m = 0; m < 8; ++m) va[k][m] = fmaf(sv[k], uv[m], va[k][m]);
  }
  #pragma unroll
  for (int k = 0; k < 4; ++k) {
    float* vp = Vg + ((size_t)b * NK + p0 + k) * NH + u0;
    *(float4*)vp       = make_float4(va[k][0], va[k][1], va[k][2], va[k][3]);
    *(float4*)(vp + 4) = make_float4(va[k][4], va[k][5], va[k][6], va[k][7]);
  }
}

// ---------------------------------------------------------------------------
// k_fuse: full per-round update for 64 rows of one batch, LDS-tiled, 16-float
// register tiles only (no big per-thread arrays -> no scratch).
// Phases: stage(h,V,aw) | msg+rank32-corr -> zm | stage w1 | t=relu(z@w1+b1)
//         | t->zh, stage w2 | out=t@w2+b2 -> global h.
// LDS: zh[64][68] zm[64][68] wb[128][68] vb[32][68] = 78336B -> 2 blk/CU.
// ---------------------------------------------------------------------------
template <bool FROMX>
__global__ __launch_bounds__(256) void k_fuse(float* __restrict__ hbuf,
                                              const float* __restrict__ x,
                                              const float* __restrict__ wn,
                                              const float* __restrict__ bn,
                                              const float* __restrict__ A_rm,
                                              const float* __restrict__ d_,
                                              const float* __restrict__ Vg,
                                              const float* __restrict__ aw,
                                              const float* __restrict__ ab,
                                              const float* __restrict__ w1,
                                              const float* __restrict__ b1,
                                              const float* __restrict__ w2,
                                              const float* __restrict__ b2) {
  __shared__ float P[19584];
  float* zh = P;            // [64][68]
  float* zm = P + 4352;     // [64][68]
  float* wb = P + 8704;     // [128][68]
  float* vb = P + 17408;    // [32][68]
  int tid = threadIdx.x;
  int bb = blockIdx.x >> 2;
  int j0 = (blockIdx.x & 3) << 6;

  // ---- P0: stage zh (h or embed-from-x), aw -> wb, V -> vb
  {
    int r = tid >> 2, c0 = (tid & 3) << 4;
    if (FROMX) {
      float xv = x[bb * ND + j0 + r];
      #pragma unroll
      for (int q = 0; q < 4; ++q) {
        float4 w = *(const float4*)(wn + (j0 + r) * NH + c0 + q * 4);
        float4 bv = *(const float4*)(bn + (j0 + r) * NH + c0 + q * 4);
        *(float4*)&zh[r * 68 + c0 + q * 4] =
            make_float4(fmaf(xv, w.x, bv.x), fmaf(xv, w.y, bv.y),
                        fmaf(xv, w.z, bv.z), fmaf(xv, w.w, bv.w));
      }
    } else {
      const float* hr = hbuf + (size_t)(bb * ND + j0 + r) * NH + c0;
      #pragma unroll
      for (int q = 0; q < 4; ++q)
        *(float4*)&zh[r * 68 + c0 + q * 4] = *(const float4*)(hr + q * 4);
    }
    #pragma unroll
    for (int q = 0; q < 4; ++q)
      *(float4*)&wb[r * 68 + c0 + q * 4] = *(const float4*)(aw + r * NH + c0 + q * 4);
    int p = tid >> 3, s8 = (tid & 7) << 3;
    const float* vsrc = Vg + (size_t)bb * NK * NH + p * NH + s8;
    *(float4*)&vb[p * 68 + s8]     = *(const float4*)(vsrc);
    *(float4*)&vb[p * 68 + s8 + 4] = *(const float4*)(vsrc + 4);
  }
  __syncthreads();

  int ri = tid >> 4, ci = tid & 15;
  int rt0 = ri * 4, ut0 = ci * 4;

  // ---- P1: msg = zh @ aw + ab ; zm = A_j @ V - d_j * msg
  {
    float acc[4][4];
    float4 abv = *(const float4*)(ab + ut0);
    #pragma unroll
    for (int i = 0; i < 4; ++i) {
      acc[i][0] = abv.x; acc[i][1] = abv.y; acc[i][2] = abv.z; acc[i][3] = abv.w;
    }
    for (int v0 = 0; v0 < NH; v0 += 4) {
      float4 b0 = *(const float4*)&wb[(v0 + 0) * 68 + ut0];
      float4 b1v = *(const float4*)&wb[(v0 + 1) * 68 + ut0];
      float4 b2v = *(const float4*)&wb[(v0 + 2) * 68 + ut0];
      float4 b3 = *(const float4*)&wb[(v0 + 3) * 68 + ut0];
      float4 a0 = *(const float4*)&zh[(rt0 + 0) * 68 + v0];
      float4 a1 = *(const float4*)&zh[(rt0 + 1) * 68 + v0];
      float4 a2 = *(const float4*)&zh[(rt0 + 2) * 68 + v0];
      float4 a3 = *(const float4*)&zh[(rt0 + 3) * 68 + v0];
      mm4(acc, a0, a1, a2, a3, b0, b1v, b2v, b3);
    }
    float fin[4][4];
    #pragma unroll
    for (int i = 0; i < 4; ++i) {
      float dv = d_[j0 + rt0 + i];
      #pragma unroll
      for (int j = 0; j < 4; ++j) fin[i][j] = -dv * acc[i][j];
    }
    for (int p0 = 0; p0 < NK; p0 += 4) {
      float4 b0 = *(const float4*)&vb[(p0 + 0) * 68 + ut0];
      float4 b1v = *(const float4*)&vb[(p0 + 1) * 68 + ut0];
      float4 b2v = *(const float4*)&vb[(p0 + 2) * 68 + ut0];
      float4 b3 = *(const float4*)&vb[(p0 + 3) * 68 + ut0];
      float4 a0 = *(const float4*)(A_rm + (j0 + rt0 + 0) * NK + p0);
      float4 a1 = *(const float4*)(A_rm + (j0 + rt0 + 1) * NK + p0);
      float4 a2 = *(const float4*)(A_rm + (j0 + rt0 + 2) * NK + p0);
      float4 a3 = *(const float4*)(A_rm + (j0 + rt0 + 3) * NK + p0);
      mm4(fin, a0, a1, a2, a3, b0, b1v, b2v, b3);
    }
    #pragma unroll
    for (int i = 0; i < 4; ++i)
      *(float4*)&zm[(rt0 + i) * 68 + ut0] =
          make_float4(fin[i][0], fin[i][1], fin[i][2], fin[i][3]);
  }
  __syncthreads();

  // ---- P2: stage w1 [128][64] into wb
  {
    int r = tid >> 2, c0 = (tid & 3) << 4;
    #pragma unroll
    for (int q = 0; q < 4; ++q) {
      *(float4*)&wb[r * 68 + c0 + q * 4] = *(const float4*)(w1 + r * NH + c0 + q * 4);
      *(float4*)&wb[(64 + r) * 68 + c0 + q * 4] =
          *(const float4*)(w1 + (64 + r) * NH + c0 + q * 4);
    }
  }
  __syncthreads();

  // ---- P3: t = relu([zh|zm] @ w1 + b1)   (kept in regs across barrier)
  float t4[4][4];
  {
    float4 b1v4 = *(const float4*)(b1 + ut0);
    #pragma unroll
    for (int i = 0; i < 4; ++i) {
      t4[i][0] = b1v4.x; t4[i][1] = b1v4.y; t4[i][2] = b1v4.z; t4[i][3] = b1v4.w;
    }
    for (int u0 = 0; u0 < NH; u0 += 4) {
      float4 b0 = *(const float4*)&wb[(u0 + 0) * 68 + ut0];
      float4 b1v = *(const float4*)&wb[(u0 + 1) * 68 + ut0];
      float4 b2v = *(const float4*)&wb[(u0 + 2) * 68 + ut0];
      float4 b3 = *(const float4*)&wb[(u0 + 3) * 68 + ut0];
      float4 a0 = *(const float4*)&zh[(rt0 + 0) * 68 + u0];
      float4 a1 = *(const float4*)&zh[(rt0 + 1) * 68 + u0];
      float4 a2 = *(const float4*)&zh[(rt0 + 2) * 68 + u0];
      float4 a3 = *(const float4*)&zh[(rt0 + 3) * 68 + u0];
      mm4(t4, a0, a1, a2, a3, b0, b1v, b2v, b3);
    }
    for (int u0 = 0; u0 < NH; u0 += 4) {
      float4 b0 = *(const float4*)&wb[(64 + u0 + 0) * 68 + ut0];
      float4 b1v = *(const float4*)&wb[(64 + u0 + 1) * 68 + ut0];
      float4 b2v = *(const float4*)&wb[(64 + u0 + 2) * 68 + ut0];
      float4 b3 = *(const float4*)&wb[(64 + u0 + 3) * 68 + ut0];
      float4 a0 = *(const float4*)&zm[(rt0 + 0) * 68 + u0];
      float4 a1 = *(const float4*)&zm[(rt0 + 1) * 68 + u0];
      float4 a2 = *(const float4*)&zm[(rt0 + 2) * 68 + u0];
      float4 a3 = *(const float4*)&zm[(rt0 + 3) * 68 + u0];
      mm4(t4, a0, a1, a2, a3, b0, b1v, b2v, b3);
    }
    #pragma unroll
    for (int i = 0; i < 4; ++i)
      #pragma unroll
      for (int j = 0; j < 4; ++j) t4[i][j] = fmaxf(t4[i][j], 0.f);
  }
  __syncthreads();

  // ---- t -> zh (zh fully consumed), stage w2 -> wb
  {
    #pragma unroll
    for (int i = 0; i < 4; ++i)
      *(float4*)&zh[(rt0 + i) * 68 + ut0] =
          make_float4(t4[i][0], t4[i][1], t4[i][2], t4[i][3]);
    int r = tid >> 2, c0 = (tid & 3) << 4;
    #pragma unroll
    for (int q = 0; q < 4; ++q)
      *(float4*)&wb[r * 68 + c0 + q * 4] = *(const float4*)(w2 + r * NH + c0 + q * 4);
  }
  __syncthreads();

  // ---- P5: out = t @ w2 + b2 -> global h
  {
    float o4[4][4];
    float4 b2v4 = *(const float4*)(b2 + ut0);
    #pragma unroll
    for (int i = 0; i < 4; ++i) {
      o4[i][0] = b2v4.x; o4[i][1] = b2v4.y; o4[i][2] = b2v4.z; o4[i][3] = b2v4.w;
    }
    for (int v0 = 0; v0 < NH; v0 += 4) {
      float4 b0 = *(const float4*)&wb[(v0 + 0) * 68 + ut0];
      float4 b1v = *(const float4*)&wb[(v0 + 1) * 68 + ut0];
      float4 b2v = *(const float4*)&wb[(v0 + 2) * 68 + ut0];
      float4 b3 = *(const float4*)&wb[(v0 + 3) * 68 + ut0];
      float4 a0 = *(const float4*)&zh[(rt0 + 0) * 68 + v0];
      float4 a1 = *(const float4*)&zh[(rt0 + 1) * 68 + v0];
      float4 a2 = *(const float4*)&zh[(rt0 + 2) * 68 + v0];
      float4 a3 = *(const float4*)&zh[(rt0 + 3) * 68 + v0];
      mm4(o4, a0, a1, a2, a3, b0, b1v, b2v, b3);
    }
    #pragma unroll
    for (int i = 0; i < 4; ++i)
      *(float4*)(hbuf + (size_t)(bb * ND + j0 + rt0 + i) * NH + ut0) =
          make_float4(o4[i][0], o4[i][1], o4[i][2], o4[i][3]);
  }
}

// ---------------------------------------------------------------------------
// k_pred1: tiled GEMM h_flat[64 rows x kch] @ p1w[kch x 128] -> part[ks].
// acc[8][4] = 32 floats/thread. grid = KS * (nbc/64) = 512 blocks always.
// ---------------------------------------------------------------------------
__global__ __launch_bounds__(256) void k_pred1(const float* __restrict__ h,
                                               const float* __restrict__ p1w,
                                               float* __restrict__ part,
                                               int lbrb, int kch, int nbc) {
  __shared__ float ws_[64 * 128];   // [kk][c]
  __shared__ float hs[64 * 64];     // [rr][kk]
  int ks = blockIdx.x >> lbrb;
  int rb = blockIdx.x & ((1 << lbrb) - 1);
  size_t rowbase = (size_t)rb * 64;
  int kbase = ks * kch;
  int t = threadIdx.x;
  int tc = t & 31, tm = t >> 5;
  float acc[8][4];
  #pragma unroll
  for (int r = 0; r < 8; ++r)
    #pragma unroll
    for (int c = 0; c < 4; ++c) acc[r][c] = 0.f;

  int nkc = kch >> 6;
  for (int kc = 0; kc < nkc; ++kc) {
    __syncthreads();
    const float* wsrc = p1w + (size_t)(kbase + kc * 64) * 128;
    for (int s = t; s < 2048; s += 256) ((float4*)ws_)[s] = ((const float4*)wsrc)[s];
    for (int s = t; s < 1024; s += 256) {
      int rr = s >> 4, q = s & 15;
      *(float4*)&hs[rr * 64 + q * 4] =
          *(const float4*)(h + (rowbase + rr) * (size_t)(ND * NH) + kbase + kc * 64 + q * 4);
    }
    __syncthreads();
    for (int kk = 0; kk < 64; kk += 4) {
      float bb[4][4];
      #pragma unroll
      for (int k = 0; k < 4; ++k) {
        float4 bv = *(const float4*)&ws_[(kk + k) * 128 + tc * 4];
        bb[k][0] = bv.x; bb[k][1] = bv.y; bb[k][2] = bv.z; bb[k][3] = bv.w;
      }
      #pragma unroll
      for (int r = 0; r < 8; ++r) {
        float4 av = *(const float4*)&hs[(tm * 8 + r) * 64 + kk];
        #pragma unroll
        for (int c = 0; c < 4; ++c)
          acc[r][c] = fmaf(av.x, bb[0][c],
                      fmaf(av.y, bb[1][c],
                      fmaf(av.z, bb[2][c],
                      fmaf(av.w, bb[3][c], acc[r][c]))));
      }
    }
  }
  float* pp = part + ((size_t)ks * nbc + rowbase) * 128;
  #pragma unroll
  for (int r = 0; r < 8; ++r)
    *(float4*)&pp[(size_t)(tm * 8 + r) * 128 + tc * 4] =
        make_float4(acc[r][0], acc[r][1], acc[r][2], acc[r][3]);
}

// ---------------------------------------------------------------------------
__global__ __launch_bounds__(256) void k_reduce(const float* __restrict__ part,
                                                const float* __restrict__ p1b,
                                                float* __restrict__ u,
                                                int kspl, int stride) {
  int idx = blockIdx.x * 256 + threadIdx.x;    // < nbc*128
  float acc = p1b[idx & 127];
  for (int ks = 0; ks < kspl; ++ks) acc += part[(size_t)ks * stride + idx];
  u[idx] = fmaxf(acc, 0.f);
}

// ---------------------------------------------------------------------------
__global__ __launch_bounds__(256) void k_pred2(const float* __restrict__ u,
                                               const float* __restrict__ p2w,
                                               const float* __restrict__ p2b,
                                               float* __restrict__ out) {
  int b = blockIdx.x * 256 + threadIdx.x;
  const float* ub = u + (size_t)b * 128;
  float acc[NC];
  #pragma unroll
  for (int c = 0; c < NC; ++c) acc[c] = p2b[c];
  #pragma unroll
  for (int q = 0; q < 32; ++q) {
    float4 uv = *(const float4*)(ub + q * 4);
    float us[4] = {uv.x, uv.y, uv.z, uv.w};
    #pragma unroll
    for (int k = 0; k < 4; ++k) {
      const float* wr = p2w + (q * 4 + k) * NC;
      #pragma unroll
      for (int c = 0; c < NC; ++c) acc[c] = fmaf(us[k], wr[c], acc[c]);
    }
  }
  float* op = out + (size_t)b * NC;
  #pragma unroll
  for (int c = 0; c < NC; ++c) op[c] = acc[c];
}

// ---------------------------------------------------------------------------
extern "C" void kernel_launch(void* const* d_in, const int* in_sizes, int n_in,
                              void* d_out, int out_size, void* d_ws, size_t ws_size,
                              hipStream_t stream) {
  const float* x           = (const float*)d_in[0];
  const float* wn          = (const float*)d_in[1];
  const float* bn          = (const float*)d_in[2];
  const float* A_raw       = (const float*)d_in[3];
  const float* priority    = (const float*)d_in[4];
  const float* edge_logits = (const float*)d_in[5];
  const float* agg_w       = (const float*)d_in[6];
  const float* agg_b       = (const float*)d_in[7];
  const float* upd_w1      = (const float*)d_in[8];
  const float* upd_b1      = (const float*)d_in[9];
  const float* upd_w2      = (const float*)d_in[10];
  const float* upd_b2      = (const float*)d_in[11];
  const float* p1w         = (const float*)d_in[12];
  const float* p1b         = (const float*)d_in[13];
  const float* p2w         = (const float*)d_in[14];
  const float* p2b         = (const float*)d_in[15];
  float* out               = (float*)d_out;

  // largest nbc tier fitting ws_size
  int nbc = 0;
  for (int cand = NB; cand >= 256 && !nbc; cand >>= 1) {
    size_t fl = 16384ull + (size_t)cand * (2048 + 16384 + 128) + 4194304ull;
    if (fl * 4 <= ws_size) nbc = cand;
  }
  if (!nbc) nbc = 256;
  int nch  = NB / nbc;
  int KS   = 32768 / nbc;           // split-K count; KS*nbc = 32768 const
  int kch  = nbc >> 1;              // 16384/KS
  int lbrb = 31 - __builtin_clz((unsigned)(nbc >> 6));   // log2(nbc/64)

  float* ws   = (float*)d_ws;
  float* A_rm = ws;                                  // 8192
  float* Sg   = ws + 8192;                           // 1024
  float* ca   = ws + 9216;                           // 64
  float* d_   = ws + 9280;                           // 256
  float* V    = ws + 16384;                          // nbc*2048
  float* h    = V + (size_t)nbc * 2048;              // nbc*16384
  float* part = h + (size_t)nbc * 16384;             // 4194304
  float* u    = part + 4194304ull;                   // nbc*128

  hipLaunchKernelGGL(k_prep, dim3(1), dim3(256), 0, stream,
                     A_raw, priority, edge_logits, A_rm, Sg, ca, d_);

  for (int c = 0; c < nch; ++c) {
    const float* xc = x + (size_t)c * nbc * ND;
    float* outc = out + (size_t)c * nbc * NC;
    // round 0 (h built from x on the fly)
    hipLaunchKernelGGL((k_r1<true>), dim3(nbc), dim3(64), 0, stream,
                       h, xc, wn, bn, A_rm, Sg, ca, agg_w, agg_b, V);
    hipLaunchKernelGGL((k_fuse<true>), dim3(nbc * 4), dim3(256), 0, stream,
                       h, xc, wn, bn, A_rm, d_, V, agg_w, agg_b,
                       upd_w1, upd_b1, upd_w2, upd_b2);
    // round 1
    hipLaunchKernelGGL((k_r1<false>), dim3(nbc), dim3(64), 0, stream,
                       h, xc, wn, bn, A_rm, Sg, ca,
                       agg_w + NH * NH, agg_b + NH, V);
    hipLaunchKernelGGL((k_fuse<false>), dim3(nbc * 4), dim3(256), 0, stream,
                       h, xc, wn, bn, A_rm, d_, V,
                       agg_w + NH * NH, agg_b + NH,
                       upd_w1 + 2 * NH * NH, upd_b1 + NH,
                       upd_w2 + NH * NH, upd_b2 + NH);
    // predictor
    hipLaunchKernelGGL(k_pred1, dim3(KS * (nbc >> 6)), dim3(256), 0, stream,
                       h, p1w, part, lbrb, kch, nbc);
    hipLaunchKernelGGL(k_reduce, dim3(nbc * 128 / 256), dim3(256), 0, stream,
                       part, p1b, u, KS, nbc * 128);
    hipLaunchKernelGGL(k_pred2, dim3(nbc / 256), dim3(256), 0, stream,
                       u, p2w, p2b, outc);
  }
}

// Round 13
// 1022.170 us; speedup vs baseline: 2.9313x; 1.7023x over previous
//
#include <hip/hip_runtime.h>
#include <math.h>

#define NB 4096
#define ND 256
#define NH 64
#define NK 32
#define NC 10
#define TAU 0.3f

typedef __attribute__((ext_vector_type(8))) short bf16x8;
typedef __attribute__((ext_vector_type(4))) float f32x4;
#define MFMA_BF16 __builtin_amdgcn_mfma_f32_16x16x32_bf16

__device__ __forceinline__ short f2bf(float f) {
  union { float f; unsigned u; } v; v.f = f;
  unsigned r = v.u + 0x7fffu + ((v.u >> 16) & 1u);   // RNE
  return (short)(r >> 16);
}

// ---------------------------------------------------------------------------
// 4x4 micro-tile FMA (kept for k_pred1, fp32 path)
// ---------------------------------------------------------------------------
__device__ __forceinline__ void mm4(float (&acc)[4][4],
                                    const float4 a0, const float4 a1,
                                    const float4 a2, const float4 a3,
                                    const float4 b0, const float4 b1,
                                    const float4 b2, const float4 b3) {
#define MM4_ROW(ai, I)                                                          \
  acc[I][0] = fmaf(ai.x, b0.x, fmaf(ai.y, b1.x, fmaf(ai.z, b2.x, fmaf(ai.w, b3.x, acc[I][0])))); \
  acc[I][1] = fmaf(ai.x, b0.y, fmaf(ai.y, b1.y, fmaf(ai.z, b2.y, fmaf(ai.w, b3.y, acc[I][1])))); \
  acc[I][2] = fmaf(ai.x, b0.z, fmaf(ai.y, b1.z, fmaf(ai.z, b2.z, fmaf(ai.w, b3.z, acc[I][2])))); \
  acc[I][3] = fmaf(ai.x, b0.w, fmaf(ai.y, b1.w, fmaf(ai.z, b2.w, fmaf(ai.w, b3.w, acc[I][3]))));
  MM4_ROW(a0, 0) MM4_ROW(a1, 1) MM4_ROW(a2, 2) MM4_ROW(a3, 3)
#undef MM4_ROW
}

// ---------------------------------------------------------------------------
// k_prep: one block, 4KB LDS. Thread t owns softmax row t (VGPRs).
// ---------------------------------------------------------------------------
__global__ __launch_bounds__(256) void k_prep(const float* __restrict__ A_raw,
                                              const float* __restrict__ priority,
                                              const float* __restrict__ edge_logits,
                                              float* __restrict__ A_rm,
                                              float* __restrict__ Sg,
                                              float* __restrict__ ca,
                                              float* __restrict__ d_) {
  __shared__ float Ss[NK][NK];
  int t = threadIdx.x;
  float a[NK];
  {
    float mx = -1e30f;
    #pragma unroll
    for (int q = 0; q < NK; ++q) { a[q] = A_raw[t * NK + q]; mx = fmaxf(mx, a[q]); }
    float s = 0.f;
    #pragma unroll
    for (int q = 0; q < NK; ++q) { a[q] = expf(a[q] - mx); s += a[q]; }
    float inv = 1.f / s;
    #pragma unroll
    for (int q = 0; q < NK; ++q) {
      a[q] *= inv;
      A_rm[t * NK + q] = a[q];
    }
  }
  for (int s = t; s < NK * NK; s += 256) {
    int p = s >> 5, q = s & 31;
    float dir = 1.f / (1.f + expf(-(priority[q] - priority[p]) / TAU));
    float edge = (edge_logits[s] > 0.f) ? 1.f : 0.f;
    float sv = (p == q) ? 0.f : edge * dir;
    Ss[p][q] = sv;
    Sg[s] = sv;
  }
  __syncthreads();
  {
    float dd = 0.f;
    #pragma unroll
    for (int p = 0; p < NK; ++p) {
      float m = 0.f;
      #pragma unroll
      for (int q = 0; q < NK; ++q) m = fmaf(a[q], Ss[q][p], m);
      dd = fmaf(m, a[p], dd);
    }
    d_[t] = dd;
  }
  if (t < NK) {
    float s = 0.f;
    for (int jj = 0; jj < ND; ++jj) s += A_rm[jj * NK + t];
    ca[t] = s;
  }
}

// ---------------------------------------------------------------------------
// k_r1: per chunk-batch (1 wave): V[b] = S^T ( (A^T h[b]) @ aw + ca (x) ab ).
// (unchanged fp32 path)
// ---------------------------------------------------------------------------
template <bool FROMX>
__global__ __launch_bounds__(64) void k_r1(const float* __restrict__ hbuf,
                                           const float* __restrict__ x,
                                           const float* __restrict__ wn,
                                           const float* __restrict__ bn,
                                           const float* __restrict__ A_rm,
                                           const float* __restrict__ Sg,
                                           const float* __restrict__ ca,
                                           const float* __restrict__ aw,
                                           const float* __restrict__ ab,
                                           float* __restrict__ Vg) {
  __shared__ float Tl[NK][68];
  __shared__ float Ul[NK][68];
  int b = blockIdx.x;
  int t = threadIdx.x;
  int ug = t & 7, pg = t >> 3;
  int p0 = pg * 4, u0 = ug * 8;

  float acc[4][8];
  #pragma unroll
  for (int k = 0; k < 4; ++k)
    #pragma unroll
    for (int m = 0; m < 8; ++m) acc[k][m] = 0.f;

  const float* hb = hbuf + (size_t)b * ND * NH;
  for (int i = 0; i < ND; ++i) {
    float hv[8];
    if (FROMX) {
      float xv = x[b * ND + i];
      float4 w0 = *(const float4*)(wn + i * NH + u0);
      float4 w1 = *(const float4*)(wn + i * NH + u0 + 4);
      float4 c0 = *(const float4*)(bn + i * NH + u0);
      float4 c1 = *(const float4*)(bn + i * NH + u0 + 4);
      hv[0] = fmaf(xv, w0.x, c0.x); hv[1] = fmaf(xv, w0.y, c0.y);
      hv[2] = fmaf(xv, w0.z, c0.z); hv[3] = fmaf(xv, w0.w, c0.w);
      hv[4] = fmaf(xv, w1.x, c1.x); hv[5] = fmaf(xv, w1.y, c1.y);
      hv[6] = fmaf(xv, w1.z, c1.z); hv[7] = fmaf(xv, w1.w, c1.w);
    } else {
      float4 h0 = *(const float4*)(hb + (size_t)i * NH + u0);
      float4 h1 = *(const float4*)(hb + (size_t)i * NH + u0 + 4);
      hv[0] = h0.x; hv[1] = h0.y; hv[2] = h0.z; hv[3] = h0.w;
      hv[4] = h1.x; hv[5] = h1.y; hv[6] = h1.z; hv[7] = h1.w;
    }
    float4 a4 = *(const float4*)(A_rm + i * NK + p0);
    float ap[4] = {a4.x, a4.y, a4.z, a4.w};
    #pragma unroll
    for (int k = 0; k < 4; ++k)
      #pragma unroll
      for (int m = 0; m < 8; ++m) acc[k][m] = fmaf(ap[k], hv[m], acc[k][m]);
  }
  #pragma unroll
  for (int k = 0; k < 4; ++k) {
    *(float4*)&Tl[p0 + k][u0]     = make_float4(acc[k][0], acc[k][1], acc[k][2], acc[k][3]);
    *(float4*)&Tl[p0 + k][u0 + 4] = make_float4(acc[k][4], acc[k][5], acc[k][6], acc[k][7]);
  }
  __syncthreads();
  float ua[4][8];
  {
    float4 b0 = *(const float4*)(ab + u0);
    float4 b1 = *(const float4*)(ab + u0 + 4);
    float abv[8] = {b0.x, b0.y, b0.z, b0.w, b1.x, b1.y, b1.z, b1.w};
    float4 c4 = *(const float4*)(ca + p0);
    float cav[4] = {c4.x, c4.y, c4.z, c4.w};
    #pragma unroll
    for (int k = 0; k < 4; ++k)
      #pragma unroll
      for (int m = 0; m < 8; ++m) ua[k][m] = cav[k] * abv[m];
  }
  for (int v = 0; v < NH; ++v) {
    float4 w0 = *(const float4*)(aw + v * NH + u0);
    float4 w1 = *(const float4*)(aw + v * NH + u0 + 4);
    float wv[8] = {w0.x, w0.y, w0.z, w0.w, w1.x, w1.y, w1.z, w1.w};
    float tv[4];
    #pragma unroll
    for (int k = 0; k < 4; ++k) tv[k] = Tl[p0 + k][v];
    #pragma unroll
    for (int k = 0; k < 4; ++k)
      #pragma unroll
      for (int m = 0; m < 8; ++m) ua[k][m] = fmaf(tv[k], wv[m], ua[k][m]);
  }
  #pragma unroll
  for (int k = 0; k < 4; ++k) {
    *(float4*)&Ul[p0 + k][u0]     = make_float4(ua[k][0], ua[k][1], ua[k][2], ua[k][3]);
    *(float4*)&Ul[p0 + k][u0 + 4] = make_float4(ua[k][4], ua[k][5], ua[k][6], ua[k][7]);
  }
  __syncthreads();
  float va[4][8];
  #pragma unroll
  for (int k = 0; k < 4; ++k)
    #pragma unroll
    for (int m = 0; m < 8; ++m) va[k][m] = 0.f;
  for (int p = 0; p < NK; ++p) {
    float4 u0v = *(const float4*)&Ul[p][u0];
    float4 u1v = *(const float4*)&Ul[p][u0 + 4];
    float uv[8] = {u0v.x, u0v.y, u0v.z, u0v.w, u1v.x, u1v.y, u1v.z, u1v.w};
    float4 s4 = *(const float4*)(Sg + p * NK + p0);
    float sv[4] = {s4.x, s4.y, s4.z, s4.w};
    #pragma unroll
    for (int k = 0; k < 4; ++k)
      #pragma unroll
      for (int m = 0; m < 8; ++m) va[k][m] = fmaf(sv[k], uv[m], va[k][m]);
  }
  #pragma unroll
  for (int k = 0; k < 4; ++k) {
    float* vp = Vg + ((size_t)b * NK + p0 + k) * NH + u0;
    *(float4*)vp       = make_float4(va[k][0], va[k][1], va[k][2], va[k][3]);
    *(float4*)(vp + 4) = make_float4(va[k][4], va[k][5], va[k][6], va[k][7]);
  }
}

// ---------------------------------------------------------------------------
// k_fuse (MFMA bf16): per-round update for 64 rows of one batch.
// 4 waves; wave w owns the 16-row output stripe [16w,16w+16) -> its A-panel
// rows are wave-private (t can overwrite zh in place, no extra barrier).
// Fragment pattern (m89/m92-verified): A row-major bf16, lane reads bf16x8 at
// row=lane&15(+stripe), k=(lane>>4)*8..+7; B stored TRANSPOSED (BT[col][k]),
// same contiguous read; C/D: col=lane&15, row=(lane>>4)*4+reg.
// Phases: P0 stage(zh,aw^T,A_rm,V^T,d,biases) | P1 msg=zh@aw+ab; acc*=-d;
// acc+=A_rm@V -> zm(bf16)->Ab[64:128] | P2 stage w1^T | P3 t=relu([zh|zm]@w1+b1)
// ->Ab[0:64] | P4 stage w2^T | P5 out=t@w2+b2 -> global h (fp32).
// LDS: Ab 17408 + Bt 17408 + Armb 5120 + Vt 5120 + 1024 = 46080 B -> 3 blk/CU.
// ---------------------------------------------------------------------------
template <bool FROMX>
__global__ __launch_bounds__(256) void k_fuse(float* __restrict__ hbuf,
                                              const float* __restrict__ x,
                                              const float* __restrict__ wn,
                                              const float* __restrict__ bn,
                                              const float* __restrict__ A_rm,
                                              const float* __restrict__ d_,
                                              const float* __restrict__ Vg,
                                              const float* __restrict__ aw,
                                              const float* __restrict__ ab,
                                              const float* __restrict__ w1,
                                              const float* __restrict__ b1,
                                              const float* __restrict__ w2,
                                              const float* __restrict__ b2) {
  __shared__ short Ab[64 * 136];    // A panel [row][k], k 0..127 used in P3
  __shared__ short Bt[64 * 136];    // B^T panel [col][k], restaged per phase
  __shared__ short Armb[64 * 40];   // A_rm rows bf16 [row][32]
  __shared__ short Vt[64 * 40];     // V^T bf16 [col][32]
  __shared__ float db[64], abb[64], b1b[64], b2b[64];

  int tid = threadIdx.x;
  int bb = blockIdx.x >> 2;
  int j0 = (blockIdx.x & 3) << 6;
  int lane = tid & 63, w = tid >> 6;
  int lr = lane & 15, kg = lane >> 4;
  int arow = w * 16 + lr;          // A-frag row (stripe-global)

  // ---- P0: staging
  {
    int r = tid >> 2, c0 = (tid & 3) << 4;    // zh/aw: 64 rows x 4 thr/row
    float vals[16];
    if (FROMX) {
      float xv = x[bb * ND + j0 + r];
      #pragma unroll
      for (int q = 0; q < 4; ++q) {
        float4 wv = *(const float4*)(wn + (j0 + r) * NH + c0 + q * 4);
        float4 bv = *(const float4*)(bn + (j0 + r) * NH + c0 + q * 4);
        vals[q * 4 + 0] = fmaf(xv, wv.x, bv.x);
        vals[q * 4 + 1] = fmaf(xv, wv.y, bv.y);
        vals[q * 4 + 2] = fmaf(xv, wv.z, bv.z);
        vals[q * 4 + 3] = fmaf(xv, wv.w, bv.w);
      }
    } else {
      const float* hr = hbuf + (size_t)(bb * ND + j0 + r) * NH + c0;
      #pragma unroll
      for (int q = 0; q < 4; ++q) {
        float4 v = *(const float4*)(hr + q * 4);
        vals[q * 4 + 0] = v.x; vals[q * 4 + 1] = v.y;
        vals[q * 4 + 2] = v.z; vals[q * 4 + 3] = v.w;
      }
    }
    short tmp[16];
    #pragma unroll
    for (int q = 0; q < 16; ++q) tmp[q] = f2bf(vals[q]);
    *(bf16x8*)&Ab[r * 136 + c0]     = *(bf16x8*)&tmp[0];
    *(bf16x8*)&Ab[r * 136 + c0 + 8] = *(bf16x8*)&tmp[8];
    // aw^T -> Bt
    #pragma unroll
    for (int q = 0; q < 4; ++q) {
      float4 v = *(const float4*)(aw + r * NH + c0 + q * 4);
      Bt[(c0 + q * 4 + 0) * 136 + r] = f2bf(v.x);
      Bt[(c0 + q * 4 + 1) * 136 + r] = f2bf(v.y);
      Bt[(c0 + q * 4 + 2) * 136 + r] = f2bf(v.z);
      Bt[(c0 + q * 4 + 3) * 136 + r] = f2bf(v.w);
    }
    // A_rm rows (row-major, no transpose)
    {
      int ar = tid >> 2, ac = (tid & 3) << 3;
      float4 a0 = *(const float4*)(A_rm + (j0 + ar) * NK + ac);
      float4 a1 = *(const float4*)(A_rm + (j0 + ar) * NK + ac + 4);
      short t8[8] = {f2bf(a0.x), f2bf(a0.y), f2bf(a0.z), f2bf(a0.w),
                     f2bf(a1.x), f2bf(a1.y), f2bf(a1.z), f2bf(a1.w)};
      *(bf16x8*)&Armb[ar * 40 + ac] = *(bf16x8*)&t8[0];
    }
    // V^T
    {
      int vr = tid >> 3, vc0 = (tid & 7) << 3;
      const float* vsrc = Vg + (size_t)bb * NK * NH + vr * NH + vc0;
      float4 v0 = *(const float4*)(vsrc);
      float4 v1 = *(const float4*)(vsrc + 4);
      Vt[(vc0 + 0) * 40 + vr] = f2bf(v0.x);
      Vt[(vc0 + 1) * 40 + vr] = f2bf(v0.y);
      Vt[(vc0 + 2) * 40 + vr] = f2bf(v0.z);
      Vt[(vc0 + 3) * 40 + vr] = f2bf(v0.w);
      Vt[(vc0 + 4) * 40 + vr] = f2bf(v1.x);
      Vt[(vc0 + 5) * 40 + vr] = f2bf(v1.y);
      Vt[(vc0 + 6) * 40 + vr] = f2bf(v1.z);
      Vt[(vc0 + 7) * 40 + vr] = f2bf(v1.w);
    }
    if (tid < 64) {
      db[tid]  = d_[j0 + tid];
      abb[tid] = ab[tid];
      b1b[tid] = b1[tid];
      b2b[tid] = b2[tid];
    }
  }
  __syncthreads();

  // ---- P1: msg = zh@aw + ab ; acc *= -d ; acc += A_rm@V  -> zm
  {
    f32x4 acc[4];
    #pragma unroll
    for (int cg = 0; cg < 4; ++cg) {
      float bv = abb[cg * 16 + lr];
      acc[cg] = (f32x4){bv, bv, bv, bv};
    }
    #pragma unroll
    for (int k0 = 0; k0 < 64; k0 += 32) {
      bf16x8 af = *(const bf16x8*)&Ab[arow * 136 + k0 + kg * 8];
      #pragma unroll
      for (int cg = 0; cg < 4; ++cg) {
        bf16x8 bfv = *(const bf16x8*)&Bt[(cg * 16 + lr) * 136 + k0 + kg * 8];
        acc[cg] = MFMA_BF16(af, bfv, acc[cg], 0, 0, 0);
      }
    }
    float dl[4];
    #pragma unroll
    for (int rg = 0; rg < 4; ++rg) dl[rg] = db[w * 16 + kg * 4 + rg];
    #pragma unroll
    for (int cg = 0; cg < 4; ++cg)
      #pragma unroll
      for (int rg = 0; rg < 4; ++rg) acc[cg][rg] *= -dl[rg];
    {
      bf16x8 af = *(const bf16x8*)&Armb[arow * 40 + kg * 8];
      #pragma unroll
      for (int cg = 0; cg < 4; ++cg) {
        bf16x8 bfv = *(const bf16x8*)&Vt[(cg * 16 + lr) * 40 + kg * 8];
        acc[cg] = MFMA_BF16(af, bfv, acc[cg], 0, 0, 0);
      }
    }
    // zm -> Ab cols 64..127 (wave-private rows)
    #pragma unroll
    for (int cg = 0; cg < 4; ++cg)
      #pragma unroll
      for (int rg = 0; rg < 4; ++rg)
        Ab[(w * 16 + kg * 4 + rg) * 136 + 64 + cg * 16 + lr] = f2bf(acc[cg][rg]);
  }
  __syncthreads();

  // ---- P2: stage w1^T [128 k][64 cols] -> Bt[col][k 0..127]
  {
    int r = tid >> 1, c0 = (tid & 1) << 5;   // r 0..127, c0 {0,32}
    #pragma unroll
    for (int q = 0; q < 8; ++q) {
      float4 v = *(const float4*)(w1 + r * NH + c0 + q * 4);
      Bt[(c0 + q * 4 + 0) * 136 + r] = f2bf(v.x);
      Bt[(c0 + q * 4 + 1) * 136 + r] = f2bf(v.y);
      Bt[(c0 + q * 4 + 2) * 136 + r] = f2bf(v.z);
      Bt[(c0 + q * 4 + 3) * 136 + r] = f2bf(v.w);
    }
  }
  __syncthreads();

  // ---- P3: t = relu([zh|zm] @ w1 + b1) -> Ab cols 0..63 (wave-private rows)
  {
    f32x4 acc[4];
    #pragma unroll
    for (int cg = 0; cg < 4; ++cg) {
      float bv = b1b[cg * 16 + lr];
      acc[cg] = (f32x4){bv, bv, bv, bv};
    }
    #pragma unroll
    for (int k0 = 0; k0 < 128; k0 += 32) {
      bf16x8 af = *(const bf16x8*)&Ab[arow * 136 + k0 + kg * 8];
      #pragma unroll
      for (int cg = 0; cg < 4; ++cg) {
        bf16x8 bfv = *(const bf16x8*)&Bt[(cg * 16 + lr) * 136 + k0 + kg * 8];
        acc[cg] = MFMA_BF16(af, bfv, acc[cg], 0, 0, 0);
      }
    }
    #pragma unroll
    for (int cg = 0; cg < 4; ++cg)
      #pragma unroll
      for (int rg = 0; rg < 4; ++rg)
        Ab[(w * 16 + kg * 4 + rg) * 136 + cg * 16 + lr] = f2bf(fmaxf(acc[cg][rg], 0.f));
  }
  __syncthreads();

  // ---- P4: stage w2^T [64][64] -> Bt
  {
    int r = tid >> 2, c0 = (tid & 3) << 4;
    #pragma unroll
    for (int q = 0; q < 4; ++q) {
      float4 v = *(const float4*)(w2 + r * NH + c0 + q * 4);
      Bt[(c0 + q * 4 + 0) * 136 + r] = f2bf(v.x);
      Bt[(c0 + q * 4 + 1) * 136 + r] = f2bf(v.y);
      Bt[(c0 + q * 4 + 2) * 136 + r] = f2bf(v.z);
      Bt[(c0 + q * 4 + 3) * 136 + r] = f2bf(v.w);
    }
  }
  __syncthreads();

  // ---- P5: out = t @ w2 + b2 -> global h (fp32)
  {
    f32x4 acc[4];
    #pragma unroll
    for (int cg = 0; cg < 4; ++cg) {
      float bv = b2b[cg * 16 + lr];
      acc[cg] = (f32x4){bv, bv, bv, bv};
    }
    #pragma unroll
    for (int k0 = 0; k0 < 64; k0 += 32) {
      bf16x8 af = *(const bf16x8*)&Ab[arow * 136 + k0 + kg * 8];
      #pragma unroll
      for (int cg = 0; cg < 4; ++cg) {
        bf16x8 bfv = *(const bf16x8*)&Bt[(cg * 16 + lr) * 136 + k0 + kg * 8];
        acc[cg] = MFMA_BF16(af, bfv, acc[cg], 0, 0, 0);
      }
    }
    #pragma unroll
    for (int cg = 0; cg < 4; ++cg)
      #pragma unroll
      for (int rg = 0; rg < 4; ++rg)
        hbuf[(size_t)(bb * ND + j0 + w * 16 + kg * 4 + rg) * NH + cg * 16 + lr] =
            acc[cg][rg];
  }
}

// ---------------------------------------------------------------------------
// k_pred1: tiled fp32 GEMM h_flat[64 rows x kch] @ p1w[kch x 128] -> part[ks].
// ---------------------------------------------------------------------------
__global__ __launch_bounds__(256) void k_pred1(const float* __restrict__ h,
                                               const float* __restrict__ p1w,
                                               float* __restrict__ part,
                                               int lbrb, int kch, int nbc) {
  __shared__ float ws_[64 * 128];   // [kk][c]
  __shared__ float hs[64 * 64];     // [rr][kk]
  int ks = blockIdx.x >> lbrb;
  int rb = blockIdx.x & ((1 << lbrb) - 1);
  size_t rowbase = (size_t)rb * 64;
  int kbase = ks * kch;
  int t = threadIdx.x;
  int tc = t & 31, tm = t >> 5;
  float acc[8][4];
  #pragma unroll
  for (int r = 0; r < 8; ++r)
    #pragma unroll
    for (int c = 0; c < 4; ++c) acc[r][c] = 0.f;

  int nkc = kch >> 6;
  for (int kc = 0; kc < nkc; ++kc) {
    __syncthreads();
    const float* wsrc = p1w + (size_t)(kbase + kc * 64) * 128;
    for (int s = t; s < 2048; s += 256) ((float4*)ws_)[s] = ((const float4*)wsrc)[s];
    for (int s = t; s < 1024; s += 256) {
      int rr = s >> 4, q = s & 15;
      *(float4*)&hs[rr * 64 + q * 4] =
          *(const float4*)(h + (rowbase + rr) * (size_t)(ND * NH) + kbase + kc * 64 + q * 4);
    }
    __syncthreads();
    for (int kk = 0; kk < 64; kk += 4) {
      float bb[4][4];
      #pragma unroll
      for (int k = 0; k < 4; ++k) {
        float4 bv = *(const float4*)&ws_[(kk + k) * 128 + tc * 4];
        bb[k][0] = bv.x; bb[k][1] = bv.y; bb[k][2] = bv.z; bb[k][3] = bv.w;
      }
      #pragma unroll
      for (int r = 0; r < 8; ++r) {
        float4 av = *(const float4*)&hs[(tm * 8 + r) * 64 + kk];
        #pragma unroll
        for (int c = 0; c < 4; ++c)
          acc[r][c] = fmaf(av.x, bb[0][c],
                      fmaf(av.y, bb[1][c],
                      fmaf(av.z, bb[2][c],
                      fmaf(av.w, bb[3][c], acc[r][c]))));
      }
    }
  }
  float* pp = part + ((size_t)ks * nbc + rowbase) * 128;
  #pragma unroll
  for (int r = 0; r < 8; ++r)
    *(float4*)&pp[(size_t)(tm * 8 + r) * 128 + tc * 4] =
        make_float4(acc[r][0], acc[r][1], acc[r][2], acc[r][3]);
}

// ---------------------------------------------------------------------------
__global__ __launch_bounds__(256) void k_reduce(const float* __restrict__ part,
                                                const float* __restrict__ p1b,
                                                float* __restrict__ u,
                                                int kspl, int stride) {
  int idx = blockIdx.x * 256 + threadIdx.x;    // < nbc*128
  float acc = p1b[idx & 127];
  for (int ks = 0; ks < kspl; ++ks) acc += part[(size_t)ks * stride + idx];
  u[idx] = fmaxf(acc, 0.f);
}

// ---------------------------------------------------------------------------
__global__ __launch_bounds__(256) void k_pred2(const float* __restrict__ u,
                                               const float* __restrict__ p2w,
                                               const float* __restrict__ p2b,
                                               float* __restrict__ out) {
  int b = blockIdx.x * 256 + threadIdx.x;
  const float* ub = u + (size_t)b * 128;
  float acc[NC];
  #pragma unroll
  for (int c = 0; c < NC; ++c) acc[c] = p2b[c];
  #pragma unroll
  for (int q = 0; q < 32; ++q) {
    float4 uv = *(const float4*)(ub + q * 4);
    float us[4] = {uv.x, uv.y, uv.z, uv.w};
    #pragma unroll
    for (int k = 0; k < 4; ++k) {
      const float* wr = p2w + (q * 4 + k) * NC;
      #pragma unroll
      for (int c = 0; c < NC; ++c) acc[c] = fmaf(us[k], wr[c], acc[c]);
    }
  }
  float* op = out + (size_t)b * NC;
  #pragma unroll
  for (int c = 0; c < NC; ++c) op[c] = acc[c];
}

// ---------------------------------------------------------------------------
extern "C" void kernel_launch(void* const* d_in, const int* in_sizes, int n_in,
                              void* d_out, int out_size, void* d_ws, size_t ws_size,
                              hipStream_t stream) {
  const float* x           = (const float*)d_in[0];
  const float* wn          = (const float*)d_in[1];
  const float* bn          = (const float*)d_in[2];
  const float* A_raw       = (const float*)d_in[3];
  const float* priority    = (const float*)d_in[4];
  const float* edge_logits = (const float*)d_in[5];
  const float* agg_w       = (const float*)d_in[6];
  const float* agg_b       = (const float*)d_in[7];
  const float* upd_w1      = (const float*)d_in[8];
  const float* upd_b1      = (const float*)d_in[9];
  const float* upd_w2      = (const float*)d_in[10];
  const float* upd_b2      = (const float*)d_in[11];
  const float* p1w         = (const float*)d_in[12];
  const float* p1b         = (const float*)d_in[13];
  const float* p2w         = (const float*)d_in[14];
  const float* p2b         = (const float*)d_in[15];
  float* out               = (float*)d_out;

  // largest nbc tier fitting ws_size
  int nbc = 0;
  for (int cand = NB; cand >= 256 && !nbc; cand >>= 1) {
    size_t fl = 16384ull + (size_t)cand * (2048 + 16384 + 128) + 4194304ull;
    if (fl * 4 <= ws_size) nbc = cand;
  }
  if (!nbc) nbc = 256;
  int nch  = NB / nbc;
  int KS   = 32768 / nbc;           // split-K count; KS*nbc = 32768 const
  int kch  = nbc >> 1;              // 16384/KS
  int lbrb = 31 - __builtin_clz((unsigned)(nbc >> 6));   // log2(nbc/64)

  float* ws   = (float*)d_ws;
  float* A_rm = ws;                                  // 8192
  float* Sg   = ws + 8192;                           // 1024
  float* ca   = ws + 9216;                           // 64
  float* d_   = ws + 9280;                           // 256
  float* V    = ws + 16384;                          // nbc*2048
  float* h    = V + (size_t)nbc * 2048;              // nbc*16384
  float* part = h + (size_t)nbc * 16384;             // 4194304
  float* u    = part + 4194304ull;                   // nbc*128

  hipLaunchKernelGGL(k_prep, dim3(1), dim3(256), 0, stream,
                     A_raw, priority, edge_logits, A_rm, Sg, ca, d_);

  for (int c = 0; c < nch; ++c) {
    const float* xc = x + (size_t)c * nbc * ND;
    float* outc = out + (size_t)c * nbc * NC;
    // round 0 (h built from x on the fly)
    hipLaunchKernelGGL((k_r1<true>), dim3(nbc), dim3(64), 0, stream,
                       h, xc, wn, bn, A_rm, Sg, ca, agg_w, agg_b, V);
    hipLaunchKernelGGL((k_fuse<true>), dim3(nbc * 4), dim3(256), 0, stream,
                       h, xc, wn, bn, A_rm, d_, V, agg_w, agg_b,
                       upd_w1, upd_b1, upd_w2, upd_b2);
    // round 1
    hipLaunchKernelGGL((k_r1<false>), dim3(nbc), dim3(64), 0, stream,
                       h, xc, wn, bn, A_rm, Sg, ca,
                       agg_w + NH * NH, agg_b + NH, V);
    hipLaunchKernelGGL((k_fuse<false>), dim3(nbc * 4), dim3(256), 0, stream,
                       h, xc, wn, bn, A_rm, d_, V,
                       agg_w + NH * NH, agg_b + NH,
                       upd_w1 + 2 * NH * NH, upd_b1 + NH,
                       upd_w2 + NH * NH, upd_b2 + NH);
    // predictor
    hipLaunchKernelGGL(k_pred1, dim3(KS * (nbc >> 6)), dim3(256), 0, stream,
                       h, p1w, part, lbrb, kch, nbc);
    hipLaunchKernelGGL(k_reduce, dim3(nbc * 128 / 256), dim3(256), 0, stream,
                       part, p1b, u, KS, nbc * 128);
    hipLaunchKernelGGL(k_pred2, dim3(nbc / 256), dim3(256), 0, stream,
                       u, p2w, p2b, outc);
  }
}